// Round 5
// baseline (190.174 us; speedup 1.0000x reference)
//
#include <hip/hip_runtime.h>

#define BS 64
#define NN 2048
#define DD 512
#define WGPB 8                 // workgroups cooperating per batch
#define CH (NN / WGPB)         // 256 rows per WG
#define NWG (BS * WGPB)        // 512 workgroups total

typedef float f32x4 __attribute__((ext_vector_type(4)));

// ---------- prelude: zero the per-batch arrival flags (every launch) ----------
__global__ void k_zero(int* __restrict__ flags) {
    if (threadIdx.x < BS) flags[threadIdx.x] = 0;
}

__device__ __forceinline__ float block_max(float x) {
    __shared__ float sm[4];
    int lane = threadIdx.x & 63, wid = threadIdx.x >> 6;
#pragma unroll
    for (int off = 32; off > 0; off >>= 1) x = fmaxf(x, __shfl_xor(x, off));
    if (lane == 0) sm[wid] = x;
    __syncthreads();
    x = fmaxf(fmaxf(sm[0], sm[1]), fmaxf(sm[2], sm[3]));
    __syncthreads();
    return x;
}
__device__ __forceinline__ float block_sum(float x) {
    __shared__ float sm[4];
    int lane = threadIdx.x & 63, wid = threadIdx.x >> 6;
#pragma unroll
    for (int off = 32; off > 0; off >>= 1) x += __shfl_xor(x, off);
    if (lane == 0) sm[wid] = x;
    __syncthreads();
    x = sm[0] + sm[1] + sm[2] + sm[3];
    __syncthreads();
    return x;
}

// ---------- fused: scores -> per-batch sync -> softmax chain -> read+write ----------
__global__ __launch_bounds__(256, 2) void k_fused(
    const float* __restrict__ M,  const float* __restrict__ kvec,
    const float* __restrict__ beta, const float* __restrict__ gp,
    const float* __restrict__ sp, const float* __restrict__ yp,
    const float* __restrict__ ep, const float* __restrict__ ap,
    const float* __restrict__ w_prev,
    float* __restrict__ score, float* __restrict__ part,
    int* __restrict__ flags,
    float* __restrict__ w_out, float* __restrict__ Mn)
{
    __shared__ float v[NN];        // full-batch gated weights (redundant per WG)
    __shared__ float wloc[CH];     // final w for my 256 rows
    __shared__ f32x4 sacc[128];

    int wg = blockIdx.x;
    int b  = wg >> 3;              // wg / WGPB
    int q  = wg & (WGPB - 1);
    int n0 = q * CH;
    int t = threadIdx.x, wave = t >> 6, lane = t & 63;

    // ================= phase a: content scores for my rows =================
    const f32x4* kr = (const f32x4*)(kvec + (size_t)b * DD);
    f32x4 k0 = kr[lane], k1 = kr[lane + 64];
    float ssk = k0.x*k0.x + k0.y*k0.y + k0.z*k0.z + k0.w*k0.w
              + k1.x*k1.x + k1.y*k1.y + k1.z*k1.z + k1.w*k1.w;
#pragma unroll
    for (int off = 32; off > 0; off >>= 1) ssk += __shfl_xor(ssk, off);
    float bscale = beta[b];

    // two rows per iteration for load-level parallelism
    for (int rloc = wave * 2; rloc < CH; rloc += 8) {
        int rowA = n0 + rloc, rowB = rowA + 1;
        const f32x4* MA = (const f32x4*)(M + ((size_t)b * NN + rowA) * DD);
        const f32x4* MB = (const f32x4*)(M + ((size_t)b * NN + rowB) * DD);
        f32x4 a0 = MA[lane], a1 = MA[lane + 64];
        f32x4 b0 = MB[lane], b1 = MB[lane + 64];
        float dotA = a0.x*k0.x + a0.y*k0.y + a0.z*k0.z + a0.w*k0.w
                   + a1.x*k1.x + a1.y*k1.y + a1.z*k1.z + a1.w*k1.w;
        float ssA  = a0.x*a0.x + a0.y*a0.y + a0.z*a0.z + a0.w*a0.w
                   + a1.x*a1.x + a1.y*a1.y + a1.z*a1.z + a1.w*a1.w;
        float dotB = b0.x*k0.x + b0.y*k0.y + b0.z*k0.z + b0.w*k0.w
                   + b1.x*k1.x + b1.y*k1.y + b1.z*k1.z + b1.w*k1.w;
        float ssB  = b0.x*b0.x + b0.y*b0.y + b0.z*b0.z + b0.w*b0.w
                   + b1.x*b1.x + b1.y*b1.y + b1.z*b1.z + b1.w*b1.w;
#pragma unroll
        for (int off = 32; off > 0; off >>= 1) {
            dotA += __shfl_xor(dotA, off);
            ssA  += __shfl_xor(ssA, off);
            dotB += __shfl_xor(dotB, off);
            ssB  += __shfl_xor(ssB, off);
        }
        if (lane == 0) {
            score[(size_t)b * NN + rowA] = bscale * dotA * rsqrtf(ssA * ssk);
            score[(size_t)b * NN + rowB] = bscale * dotB * rsqrtf(ssB * ssk);
        }
    }

    // ================= per-batch sync (device-scope release/acquire) ========
    __syncthreads();
    if (t == 0) {
        __threadfence();
        __hip_atomic_fetch_add(flags + b, 1, __ATOMIC_RELEASE, __HIP_MEMORY_SCOPE_AGENT);
        int it = 0;
        while (__hip_atomic_load(flags + b, __ATOMIC_ACQUIRE, __HIP_MEMORY_SCOPE_AGENT) < WGPB
               && ++it < (1 << 20)) {
            __builtin_amdgcn_s_sleep(8);
        }
        __threadfence();
    }
    __syncthreads();

    // ================= phase b: softmax + gate + conv + sharpen (redundant) =
    float g = gp[b], y = yp[b];
    float s0 = sp[b * 3 + 0], s1 = sp[b * 3 + 1], s2 = sp[b * 3 + 2];

    float loc[8];
    float mx = -1e30f;
#pragma unroll
    for (int i = 0; i < 8; ++i) {
        loc[i] = score[(size_t)b * NN + t * 8 + i];
        mx = fmaxf(mx, loc[i]);
    }
    mx = block_max(mx);
    float sum = 0.f;
#pragma unroll
    for (int i = 0; i < 8; ++i) {
        loc[i] = __expf(loc[i] - mx);
        sum += loc[i];
    }
    sum = block_sum(sum);
    float inv = 1.f / sum;
#pragma unroll
    for (int i = 0; i < 8; ++i) {
        int n = t * 8 + i;
        v[n] = g * loc[i] * inv + (1.f - g) * w_prev[(size_t)b * NN + n];
    }
    __syncthreads();
    float u[8];
    float psum = 0.f;
#pragma unroll
    for (int i = 0; i < 8; ++i) {
        int n  = t * 8 + i;
        int nm = (n == 0) ? NN - 1 : n - 1;
        int np = (n == NN - 1) ? 0 : n + 1;
        float uu = s2 * v[nm] + s1 * v[n] + s0 * v[np];
        uu = powf(uu, y);
        u[i] = uu;
        psum += uu;
    }
    psum = block_sum(psum);
    float pin = 1.f / psum;
#pragma unroll
    for (int i = 0; i < 8; ++i) {
        int n = t * 8 + i;
        if ((n >> 8) == q) {                    // CH == 256
            float wf = u[i] * pin;
            w_out[(size_t)b * NN + n] = wf;
            wloc[n & (CH - 1)] = wf;
        }
    }
    __syncthreads();

    // ================= phase c: M_next + partial r for my rows ==============
    int c  = t & 127;
    int rh = t >> 7;
    const f32x4* e4 = (const f32x4*)(ep + (size_t)b * DD);
    const f32x4* a4 = (const f32x4*)(ap + (size_t)b * DD);
    f32x4 ev = e4[c], av = a4[c];
    f32x4 acc = (f32x4)(0.f);

    const f32x4* Mb  = (const f32x4*)(M  + ((size_t)b * NN + n0) * DD);
    f32x4*       Mnb = (f32x4*)      (Mn + ((size_t)b * NN + n0) * DD);

    for (int i = 0; i < CH / 16; ++i) {
        float wv[8];
        f32x4 m4[8];
#pragma unroll
        for (int j = 0; j < 8; ++j) {
            int rr = (i * 8 + j) * 2 + rh;
            wv[j] = wloc[rr];
            m4[j] = __builtin_nontemporal_load(&Mb[(size_t)rr * 128 + c]);
        }
#pragma unroll
        for (int j = 0; j < 8; ++j) {
            int rr = (i * 8 + j) * 2 + rh;
            acc += wv[j] * m4[j];
            f32x4 o = m4[j] * (1.f - wv[j] * ev) + wv[j] * av;
            __builtin_nontemporal_store(o, &Mnb[(size_t)rr * 128 + c]);
        }
    }

    if (rh == 1) sacc[c] = acc;
    __syncthreads();
    if (rh == 0) {
        acc += sacc[c];
        ((f32x4*)(part + (size_t)wg * DD))[c] = acc;
    }
}

// ---------- reduce partial r ----------
__global__ __launch_bounds__(256) void k_reduce(const float* __restrict__ part,
                                               float* __restrict__ r) {
    int b  = blockIdx.x;
    int t  = threadIdx.x;
    int c  = t & 127;
    int rh = t >> 7;
    const f32x4* pb = (const f32x4*)(part + (size_t)b * WGPB * DD);
    f32x4 acc = (f32x4)(0.f);
    for (int j = rh * (WGPB / 2); j < (rh + 1) * (WGPB / 2); ++j) {
        acc += pb[(size_t)j * 128 + c];
    }
    __shared__ f32x4 sacc[128];
    if (rh == 1) sacc[c] = acc;
    __syncthreads();
    if (rh == 0) {
        acc += sacc[c];
        ((f32x4*)(r + (size_t)b * DD))[c] = acc;
    }
}

extern "C" void kernel_launch(void* const* d_in, const int* in_sizes, int n_in,
                              void* d_out, int out_size, void* d_ws, size_t ws_size,
                              hipStream_t stream) {
    const float* M      = (const float*)d_in[0];
    const float* k      = (const float*)d_in[1];
    const float* beta   = (const float*)d_in[2];
    const float* g      = (const float*)d_in[3];
    const float* s      = (const float*)d_in[4];
    const float* y      = (const float*)d_in[5];
    const float* e      = (const float*)d_in[6];
    const float* a      = (const float*)d_in[7];
    const float* w_prev = (const float*)d_in[8];

    float* out = (float*)d_out;
    float* r   = out;                       // [BS, DD]
    float* w   = out + BS * DD;             // [BS, NN]
    float* Mn  = out + BS * DD + BS * NN;   // [BS, NN, DD]

    int*   flags = (int*)d_ws;                       // 64 ints (256 B)
    float* score = (float*)d_ws + 64;                // BS*NN floats (512 KB)
    float* part  = score + (size_t)BS * NN;          // NWG*DD floats (1 MB)

    k_zero  <<<1,   64, 0, stream>>>(flags);
    k_fused <<<NWG, 256, 0, stream>>>(M, k, beta, g, s, y, e, a, w_prev,
                                      score, part, flags, w, Mn);
    k_reduce<<<BS,  256, 0, stream>>>(part, r);
}